// Round 5
// baseline (239.647 us; speedup 1.0000x reference)
//
#include <hip/hip_runtime.h>
#include <hip/hip_bf16.h>

#define S_DIM 128
#define R_DIM 256
#define CM    256
#define CH    32
#define CZ    128

using bf16x8 = __attribute__((ext_vector_type(8))) short;
using f32x4  = __attribute__((ext_vector_type(4))) float;

static __device__ __forceinline__ unsigned short f2bf(float f) {
    __hip_bfloat16 h = __float2bfloat16(f);
    return *reinterpret_cast<unsigned short*>(&h);
}

// ---------------------------------------------------------------------------
// Prep 1: w12T [h64][c256] bf16 | wTp [z128][k'=e*32+c] bf16 | maskT [r][s]
// ---------------------------------------------------------------------------
__global__ __launch_bounds__(256)
void prep1_kernel(const float* __restrict__ w1, const float* __restrict__ w2,
                  const float* __restrict__ w_out, const float* __restrict__ mask,
                  __hip_bfloat16* __restrict__ w12T, __hip_bfloat16* __restrict__ wT,
                  float* __restrict__ maskT)
{
    const int b = blockIdx.x, tid = threadIdx.x;
    if (b < 64) {
        const int idx = b * 256 + tid;                 // 16384
        const int h = idx >> 8, c = idx & 255;
        const float v = (h < 32) ? w1[c * CH + h] : w2[c * CH + (h - 32)];
        w12T[idx] = __float2bfloat16(v);
    } else if (b < 576) {
        const int idx = (b - 64) * 256 + tid;          // 131072, dest-ordered
        const int z = idx >> 10, kp = idx & 1023;
        const int e = kp >> 5, c = kp & 31;
        wT[idx] = __float2bfloat16(w_out[(c * 32 + e) * CZ + z]);
    } else {
        const int idx = (b - 576) * 256 + tid;         // 32768
        const int s = idx & 127, r = idx >> 7;
        maskT[r * S_DIM + s] = mask[s * R_DIM + r];
    }
}

// ---------------------------------------------------------------------------
// Prep 2: recip norm from maskT (float4 dots)
// ---------------------------------------------------------------------------
__global__ __launch_bounds__(256)
void prep2_kernel(const float* __restrict__ maskT, float* __restrict__ rcp)
{
    const int i = blockIdx.x, j = threadIdx.x;
    const float4* ci = reinterpret_cast<const float4*>(maskT + i * S_DIM);
    const float4* cj = reinterpret_cast<const float4*>(maskT + j * S_DIM);
    float acc = 0.f;
    #pragma unroll 8
    for (int t = 0; t < 32; ++t) {
        const float4 a = ci[t], b = cj[t];
        acc += a.x * b.x + a.y * b.y + a.z * b.z + a.w * b.w;
    }
    rcp[i * R_DIM + j] = 1.0f / (acc + 1e-3f);
}

// ---------------------------------------------------------------------------
// Kernel 1: LayerNorm -> bf16 LDS tile -> MFMA 256->64 projection
// wg covers 2 r x 16 s (32 rows); epilogue packs 4 consecutive s per store.
// a_t/b_t layout: [r][h][s]
// ---------------------------------------------------------------------------
__global__ __launch_bounds__(256)
void ln_proj_kernel(const float* __restrict__ m, const float* __restrict__ mask,
                    const float* __restrict__ ls, const float* __restrict__ lb,
                    const __hip_bfloat16* __restrict__ w12T,
                    const float* __restrict__ b1v, const float* __restrict__ b2v,
                    __hip_bfloat16* __restrict__ a_t, __hip_bfloat16* __restrict__ b_t)
{
    __shared__ unsigned short X[32 * 256];   // 16 KB
    const int tid  = threadIdx.x;
    const int wave = tid >> 6, lane = tid & 63;
    const int l16 = lane & 15, l4 = lane >> 4;
    const int rb = blockIdx.x & 127, sb = blockIdx.x >> 7;
    const int r0 = rb * 2, s0 = sb * 16;
    char* Xb = reinterpret_cast<char*>(X);

    const float4 sc = *reinterpret_cast<const float4*>(ls + lane * 4);
    const float4 bi = *reinterpret_cast<const float4*>(lb + lane * 4);

    for (int rep = 0; rep < 8; ++rep) {
        const int row = wave * 8 + rep;          // row = rl*16 + sl
        const int rl = row >> 4, sl = row & 15;
        const float4 x = *reinterpret_cast<const float4*>(
            m + ((size_t)(s0 + sl) * R_DIM + r0 + rl) * CM + lane * 4);
        float sum = x.x + x.y + x.z + x.w;
        float sq  = x.x * x.x + x.y * x.y + x.z * x.z + x.w * x.w;
        #pragma unroll
        for (int off = 32; off; off >>= 1) {
            sum += __shfl_xor(sum, off);
            sq  += __shfl_xor(sq, off);
        }
        const float mu = sum * (1.0f / CM);
        const float rs = rsqrtf(sq * (1.0f / CM) - mu * mu + 1e-5f);
        ushort4 o;
        o.x = f2bf((x.x - mu) * rs * sc.x + bi.x);
        o.y = f2bf((x.y - mu) * rs * sc.y + bi.y);
        o.z = f2bf((x.z - mu) * rs * sc.z + bi.z);
        o.w = f2bf((x.w - mu) * rs * sc.w + bi.w);
        const int byte = (row * 512 + lane * 8) ^ ((row & 7) << 4);
        *reinterpret_cast<ushort4*>(Xb + byte) = o;
    }
    __syncthreads();

    // waves: wm = m-tile (16 rows = 1 r x 16 s), wn = a|b half
    const int wm = wave >> 1, wn = wave & 1;
    const f32x4 zero = {0.f, 0.f, 0.f, 0.f};
    f32x4 acc[2];
    acc[0] = zero; acc[1] = zero;
    const int arow = wm * 16 + l16;
    const int asw  = (arow & 7) << 4;
    const char* arb = Xb + arow * 512;
    const __hip_bfloat16* wbase = w12T + (size_t)(wn * 32 + l16) * CM + l4 * 8;

    #pragma unroll
    for (int kb = 0; kb < 8; ++kb) {
        const bf16x8 af = *reinterpret_cast<const bf16x8*>(arb + ((kb * 64 + l4 * 16) ^ asw));
        #pragma unroll
        for (int nt = 0; nt < 2; ++nt) {
            const bf16x8 bf = *reinterpret_cast<const bf16x8*>(wbase + nt * 16 * CM + kb * 32);
            acc[nt] = __builtin_amdgcn_mfma_f32_16x16x32_bf16(af, bf, acc[nt], 0, 0, 0);
        }
    }

    __hip_bfloat16* dst = wn ? b_t : a_t;
    const float*    bv  = wn ? b2v : b1v;
    const int r = r0 + wm;
    float mk[4];
    #pragma unroll
    for (int t = 0; t < 4; ++t)
        mk[t] = mask[(s0 + l4 * 4 + t) * R_DIM + r];   // D-row = s-local = l4*4+t

    #pragma unroll
    for (int nt = 0; nt < 2; ++nt) {
        const int h = nt * 16 + l16;
        const float bo = bv[h];
        ushort4 o;
        o.x = f2bf((acc[nt][0] + bo) * mk[0]);
        o.y = f2bf((acc[nt][1] + bo) * mk[1]);
        o.z = f2bf((acc[nt][2] + bo) * mk[2]);
        o.w = f2bf((acc[nt][3] + bo) * mk[3]);
        *reinterpret_cast<ushort4*>(
            reinterpret_cast<unsigned short*>(dst) +
            (size_t)r * (CH * S_DIM) + h * S_DIM + s0 + l4 * 4) = o;
    }
}

// ---------------------------------------------------------------------------
// Kernel 2: fused outer-product (K=S=128) + w_out projection (K'=1024)
// WG = 8 i x 4 j = 32 pairs, ONE pass, ONE barrier. 64 KB LDS, 2 wgs/CU.
// Phase 1: wave owns i=i0+wave, loops 4 j software-pipelined (bfr dbuf).
// Outer tile TRANSPOSED [pair][e][c]; 4 ds_write_b64 per j.
// Phase 2: wave owns 16 z, loops 2 m-tiles x 32 kb, wf/ar double-buffered.
// ---------------------------------------------------------------------------
__global__ __launch_bounds__(512)
void fused_kernel(const __hip_bfloat16* __restrict__ a_t,
                  const __hip_bfloat16* __restrict__ b_t,
                  const __hip_bfloat16* __restrict__ wT,
                  const float* __restrict__ b_out,
                  const float* __restrict__ recip,
                  float* __restrict__ out)
{
    __shared__ __hip_bfloat16 outer_lds[32 * 1024];   // 64 KB
    const int tid  = threadIdx.x;
    const int wave = tid >> 6, lane = tid & 63;
    const int l16 = lane & 15, l4 = lane >> 4;
    const int i0 = blockIdx.y * 8, j0 = blockIdx.x * 4;
    char* ldsb = reinterpret_cast<char*>(outer_lds);

    // ---- phase 1 ----
    {
        const int i = i0 + wave;
        const __hip_bfloat16* abase = a_t + (size_t)i * (CH * S_DIM) + l16 * S_DIM + l4 * 8;
        bf16x8 afr[2][4];
        #pragma unroll
        for (int ch = 0; ch < 2; ++ch)
            #pragma unroll
            for (int kk = 0; kk < 4; ++kk)
                afr[ch][kk] = *reinterpret_cast<const bf16x8*>(abase + ch * 16 * S_DIM + kk * 32);

        bf16x8 bfr[2][2][4];    // [buf][eh][kk]
        {
            const __hip_bfloat16* bb = b_t + (size_t)j0 * (CH * S_DIM) + l16 * S_DIM + l4 * 8;
            #pragma unroll
            for (int eh = 0; eh < 2; ++eh)
                #pragma unroll
                for (int kk = 0; kk < 4; ++kk)
                    bfr[0][eh][kk] = *reinterpret_cast<const bf16x8*>(bb + eh * 16 * S_DIM + kk * 32);
        }

        #pragma unroll
        for (int j = 0; j < 4; ++j) {
            const int cur = j & 1, nxt = cur ^ 1;
            if (j < 3) {
                const __hip_bfloat16* bb = b_t + (size_t)(j0 + j + 1) * (CH * S_DIM) + l16 * S_DIM + l4 * 8;
                #pragma unroll
                for (int eh = 0; eh < 2; ++eh)
                    #pragma unroll
                    for (int kk = 0; kk < 4; ++kk)
                        bfr[nxt][eh][kk] = *reinterpret_cast<const bf16x8*>(bb + eh * 16 * S_DIM + kk * 32);
            }
            const f32x4 zero = {0.f, 0.f, 0.f, 0.f};
            f32x4 acc[2][2];
            acc[0][0] = zero; acc[0][1] = zero; acc[1][0] = zero; acc[1][1] = zero;
            #pragma unroll
            for (int kk = 0; kk < 4; ++kk) {
                acc[0][0] = __builtin_amdgcn_mfma_f32_16x16x32_bf16(afr[0][kk], bfr[cur][0][kk], acc[0][0], 0, 0, 0);
                acc[0][1] = __builtin_amdgcn_mfma_f32_16x16x32_bf16(afr[0][kk], bfr[cur][1][kk], acc[0][1], 0, 0, 0);
                acc[1][0] = __builtin_amdgcn_mfma_f32_16x16x32_bf16(afr[1][kk], bfr[cur][0][kk], acc[1][0], 0, 0, 0);
                acc[1][1] = __builtin_amdgcn_mfma_f32_16x16x32_bf16(afr[1][kk], bfr[cur][1][kk], acc[1][1], 0, 0, 0);
            }
            const int pair = wave * 4 + j;             // 0..31
            char* rowb = ldsb + pair * 2048;
            const int psw = (pair & 7) << 4;
            #pragma unroll
            for (int ch = 0; ch < 2; ++ch)
                #pragma unroll
                for (int eh = 0; eh < 2; ++eh) {
                    const int e  = eh * 16 + l16;
                    const int c0 = ch * 16 + l4 * 4;
                    const int byte = (e * 64 + c0 * 2) ^ ((e & 3) << 4) ^ psw;
                    ushort4 o;
                    o.x = f2bf(acc[ch][eh][0]);
                    o.y = f2bf(acc[ch][eh][1]);
                    o.z = f2bf(acc[ch][eh][2]);
                    o.w = f2bf(acc[ch][eh][3]);
                    *reinterpret_cast<ushort4*>(rowb + byte) = o;
                }
        }
    }
    __syncthreads();

    // ---- phase 2: [32 pairs x 1024] @ wTp^T -> [32 x 128] ----
    {
        const __hip_bfloat16* wbase = wT + (size_t)(wave * 16 + l16) * 1024 + l4 * 8;
        const f32x4 zero = {0.f, 0.f, 0.f, 0.f};
        f32x4 pacc[2];
        pacc[0] = zero; pacc[1] = zero;

        bf16x8 wf[2];
        bf16x8 ar[2][2];   // [buf][mt]
        wf[0] = *reinterpret_cast<const bf16x8*>(wbase);
        #pragma unroll
        for (int mt = 0; mt < 2; ++mt) {
            const int pr = mt * 16 + l16;
            ar[0][mt] = *reinterpret_cast<const bf16x8*>(
                ldsb + pr * 2048 + ((l4 * 16) ^ ((pr & 7) << 4)));
        }

        for (int kb = 0; kb < 32; ++kb) {
            const int cur = kb & 1, nxt = cur ^ 1;
            if (kb < 31) {
                const int kn = kb + 1;
                wf[nxt] = *reinterpret_cast<const bf16x8*>(wbase + kn * 32);
                #pragma unroll
                for (int mt = 0; mt < 2; ++mt) {
                    const int pr = mt * 16 + l16;
                    ar[nxt][mt] = *reinterpret_cast<const bf16x8*>(
                        ldsb + pr * 2048 +
                        ((kn * 64 + l4 * 16) ^ ((kn & 3) << 4) ^ ((pr & 7) << 4)));
                }
            }
            pacc[0] = __builtin_amdgcn_mfma_f32_16x16x32_bf16(ar[cur][0], wf[cur], pacc[0], 0, 0, 0);
            pacc[1] = __builtin_amdgcn_mfma_f32_16x16x32_bf16(ar[cur][1], wf[cur], pacc[1], 0, 0, 0);
        }

        const int z = wave * 16 + l16;
        const float bo = b_out[z];
        #pragma unroll
        for (int mt = 0; mt < 2; ++mt) {
            #pragma unroll
            for (int t = 0; t < 4; ++t) {
                const int pl = mt * 16 + l4 * 4 + t;          // pair-local
                const int oi = i0 + (pl >> 2), oj = j0 + (pl & 3);
                out[((size_t)oi * R_DIM + oj) * CZ + z] =
                    (pacc[mt][t] + bo) * recip[oi * R_DIM + oj];
            }
        }
    }
}

// ---------------------------------------------------------------------------
extern "C" void kernel_launch(void* const* d_in, const int* in_sizes, int n_in,
                              void* d_out, int out_size, void* d_ws, size_t ws_size,
                              hipStream_t stream)
{
    const float* m     = (const float*)d_in[0];
    const float* mask  = (const float*)d_in[1];
    const float* ln_s  = (const float*)d_in[2];
    const float* ln_b  = (const float*)d_in[3];
    const float* w1    = (const float*)d_in[4];
    const float* b1    = (const float*)d_in[5];
    const float* w2    = (const float*)d_in[6];
    const float* b2    = (const float*)d_in[7];
    const float* w_out = (const float*)d_in[8];
    const float* b_out = (const float*)d_in[9];
    float* out = (float*)d_out;

    char* ws = (char*)d_ws;
    __hip_bfloat16* a_t   = (__hip_bfloat16*)(ws);                                     // 2 MB
    __hip_bfloat16* b_t   = (__hip_bfloat16*)(ws + (size_t)(2u << 20));                // 2 MB
    __hip_bfloat16* wT    = (__hip_bfloat16*)(ws + (size_t)(4u << 20));                // 256 KB
    float*          rcp   = (float*)(ws + (size_t)(4u << 20) + (size_t)(256u << 10));  // 256 KB
    __hip_bfloat16* w12T  = (__hip_bfloat16*)(ws + (size_t)(4u << 20) + (size_t)(512u << 10)); // 32 KB
    float*          maskT = (float*)(ws + (size_t)(4u << 20) + (size_t)(544u << 10));  // 128 KB

    prep1_kernel<<<704, 256, 0, stream>>>(w1, w2, w_out, mask, w12T, wT, maskT);
    prep2_kernel<<<R_DIM, R_DIM, 0, stream>>>(maskT, rcp);
    ln_proj_kernel<<<1024, 256, 0, stream>>>(m, mask, ln_s, ln_b, w12T, b1, b2, a_t, b_t);
    fused_kernel<<<dim3(64, 32), 512, 0, stream>>>(a_t, b_t, wT, b_out, rcp, out);
}

// Round 7
// 167.971 us; speedup vs baseline: 1.4267x; 1.4267x over previous
//
#include <hip/hip_runtime.h>
#include <hip/hip_bf16.h>
#include <stdint.h>

#define S_DIM 128
#define R_DIM 256
#define CM    256
#define CH    32
#define CZ    128

using bf16x8 = __attribute__((ext_vector_type(8))) short;
using f32x4  = __attribute__((ext_vector_type(4))) float;

static __device__ __forceinline__ unsigned short f2bf(float f) {
    __hip_bfloat16 h = __float2bfloat16(f);
    return *reinterpret_cast<unsigned short*>(&h);
}

// ---------------------------------------------------------------------------
// Prep 1: w12T [h64][c256] bf16 | wTp [z128][k'=e*32+c] bf16 | maskT [r][s]
// ---------------------------------------------------------------------------
__global__ __launch_bounds__(256)
void prep1_kernel(const float* __restrict__ w1, const float* __restrict__ w2,
                  const float* __restrict__ w_out, const float* __restrict__ mask,
                  __hip_bfloat16* __restrict__ w12T, __hip_bfloat16* __restrict__ wT,
                  float* __restrict__ maskT)
{
    const int b = blockIdx.x, tid = threadIdx.x;
    if (b < 64) {
        const int idx = b * 256 + tid;                 // 16384
        const int h = idx >> 8, c = idx & 255;
        const float v = (h < 32) ? w1[c * CH + h] : w2[c * CH + (h - 32)];
        w12T[idx] = __float2bfloat16(v);
    } else if (b < 576) {
        const int idx = (b - 64) * 256 + tid;          // 131072, dest-ordered
        const int z = idx >> 10, kp = idx & 1023;
        const int e = kp >> 5, c = kp & 31;
        wT[idx] = __float2bfloat16(w_out[(c * 32 + e) * CZ + z]);
    } else {
        const int idx = (b - 576) * 256 + tid;         // 32768
        const int s = idx & 127, r = idx >> 7;
        maskT[r * S_DIM + s] = mask[s * R_DIM + r];
    }
}

// ---------------------------------------------------------------------------
// Prep 2: recip norm from maskT (float4 dots)
// ---------------------------------------------------------------------------
__global__ __launch_bounds__(256)
void prep2_kernel(const float* __restrict__ maskT, float* __restrict__ rcp)
{
    const int i = blockIdx.x, j = threadIdx.x;
    const float4* ci = reinterpret_cast<const float4*>(maskT + i * S_DIM);
    const float4* cj = reinterpret_cast<const float4*>(maskT + j * S_DIM);
    float acc = 0.f;
    #pragma unroll 8
    for (int t = 0; t < 32; ++t) {
        const float4 a = ci[t], b = cj[t];
        acc += a.x * b.x + a.y * b.y + a.z * b.z + a.w * b.w;
    }
    rcp[i * R_DIM + j] = 1.0f / (acc + 1e-3f);
}

// ---------------------------------------------------------------------------
// Kernel 1: LayerNorm -> bf16 LDS tile -> MFMA 256->64 projection
// a_t layout: [r][h][s] plain.  b_t layout: [r][h][s] with byte swizzle
// byte ^= ((h&7)<<4) within each 256B h-row (iff bswz), so consumers'
// ds_read_b128 at h-stride 256B are conflict-free after linear LDS staging.
// ---------------------------------------------------------------------------
__global__ __launch_bounds__(256)
void ln_proj_kernel(const float* __restrict__ m, const float* __restrict__ mask,
                    const float* __restrict__ ls, const float* __restrict__ lb,
                    const __hip_bfloat16* __restrict__ w12T,
                    const float* __restrict__ b1v, const float* __restrict__ b2v,
                    __hip_bfloat16* __restrict__ a_t, __hip_bfloat16* __restrict__ b_t,
                    int bswz)
{
    __shared__ unsigned short X[32 * 256];   // 16 KB
    const int tid  = threadIdx.x;
    const int wave = tid >> 6, lane = tid & 63;
    const int l16 = lane & 15, l4 = lane >> 4;
    const int rb = blockIdx.x & 127, sb = blockIdx.x >> 7;
    const int r0 = rb * 2, s0 = sb * 16;
    char* Xb = reinterpret_cast<char*>(X);

    const float4 sc = *reinterpret_cast<const float4*>(ls + lane * 4);
    const float4 bi = *reinterpret_cast<const float4*>(lb + lane * 4);

    for (int rep = 0; rep < 8; ++rep) {
        const int row = wave * 8 + rep;          // row = rl*16 + sl
        const int rl = row >> 4, sl = row & 15;
        const float4 x = *reinterpret_cast<const float4*>(
            m + ((size_t)(s0 + sl) * R_DIM + r0 + rl) * CM + lane * 4);
        float sum = x.x + x.y + x.z + x.w;
        float sq  = x.x * x.x + x.y * x.y + x.z * x.z + x.w * x.w;
        #pragma unroll
        for (int off = 32; off; off >>= 1) {
            sum += __shfl_xor(sum, off);
            sq  += __shfl_xor(sq, off);
        }
        const float mu = sum * (1.0f / CM);
        const float rs = rsqrtf(sq * (1.0f / CM) - mu * mu + 1e-5f);
        ushort4 o;
        o.x = f2bf((x.x - mu) * rs * sc.x + bi.x);
        o.y = f2bf((x.y - mu) * rs * sc.y + bi.y);
        o.z = f2bf((x.z - mu) * rs * sc.z + bi.z);
        o.w = f2bf((x.w - mu) * rs * sc.w + bi.w);
        const int byte = (row * 512 + lane * 8) ^ ((row & 7) << 4);
        *reinterpret_cast<ushort4*>(Xb + byte) = o;
    }
    __syncthreads();

    // waves: wm = m-tile (16 rows = 1 r x 16 s), wn = a|b half
    const int wm = wave >> 1, wn = wave & 1;
    const f32x4 zero = {0.f, 0.f, 0.f, 0.f};
    f32x4 acc[2];
    acc[0] = zero; acc[1] = zero;
    const int arow = wm * 16 + l16;
    const int asw  = (arow & 7) << 4;
    const char* arb = Xb + arow * 512;
    const __hip_bfloat16* wbase = w12T + (size_t)(wn * 32 + l16) * CM + l4 * 8;

    #pragma unroll
    for (int kb = 0; kb < 8; ++kb) {
        const bf16x8 af = *reinterpret_cast<const bf16x8*>(arb + ((kb * 64 + l4 * 16) ^ asw));
        #pragma unroll
        for (int nt = 0; nt < 2; ++nt) {
            const bf16x8 bf = *reinterpret_cast<const bf16x8*>(wbase + nt * 16 * CM + kb * 32);
            acc[nt] = __builtin_amdgcn_mfma_f32_16x16x32_bf16(af, bf, acc[nt], 0, 0, 0);
        }
    }

    const float* bv = wn ? b2v : b1v;
    const int r = r0 + wm;
    float mk[4];
    #pragma unroll
    for (int t = 0; t < 4; ++t)
        mk[t] = mask[(s0 + l4 * 4 + t) * R_DIM + r];   // D-row = s-local = l4*4+t

    #pragma unroll
    for (int nt = 0; nt < 2; ++nt) {
        const int h = nt * 16 + l16;
        const float bo = bv[h];
        ushort4 o;
        o.x = f2bf((acc[nt][0] + bo) * mk[0]);
        o.y = f2bf((acc[nt][1] + bo) * mk[1]);
        o.z = f2bf((acc[nt][2] + bo) * mk[2]);
        o.w = f2bf((acc[nt][3] + bo) * mk[3]);
        const int sbyte = (s0 + l4 * 4) * 2;
        if (wn == 0) {
            *reinterpret_cast<ushort4*>(
                reinterpret_cast<char*>(a_t) + (size_t)r * 8192 + h * 256 + sbyte) = o;
        } else {
            const int swz = bswz ? ((h & 7) << 4) : 0;
            *reinterpret_cast<ushort4*>(
                reinterpret_cast<char*>(b_t) + (size_t)r * 8192 + h * 256 + (sbyte ^ swz)) = o;
        }
    }
}

// ---------------------------------------------------------------------------
// Kernel 2a (split path): outer products -> OU [p=i*256+j][k'=e*32+c] bf16
// wg = 8i x 8j; b-tile (8 swizzled rows, 64 KB) staged ONCE via
// global_load_lds; wave owns i=i0+wave, loops 8 j from LDS; writes OU
// straight from accumulators (4 x ushort4 per pair).
// ---------------------------------------------------------------------------
__global__ __launch_bounds__(512)
void outer_kernel(const __hip_bfloat16* __restrict__ a_t,
                  const __hip_bfloat16* __restrict__ b_t,   // swizzled rows
                  __hip_bfloat16* __restrict__ OU)
{
    __shared__ char Bs[8 * 8192];   // 64 KB
    const int tid  = threadIdx.x;
    const int wave = tid >> 6, lane = tid & 63;
    const int l16 = lane & 15, l4 = lane >> 4;
    const int i0 = blockIdx.x * 8, j0 = blockIdx.y * 8;

    // a-fragments for this wave's i (plain layout), issued before staging
    const int i = i0 + wave;
    const __hip_bfloat16* abase = a_t + (size_t)i * (CH * S_DIM) + l16 * S_DIM + l4 * 8;
    bf16x8 afr[2][4];
    #pragma unroll
    for (int ch = 0; ch < 2; ++ch)
        #pragma unroll
        for (int kk = 0; kk < 4; ++kk)
            afr[ch][kk] = *reinterpret_cast<const bf16x8*>(abase + ch * 16 * S_DIM + kk * 32);

    // stage 8 swizzled b-rows linearly (64 KB = 4096 x 16B chunks)
    const char* bsrc = reinterpret_cast<const char*>(b_t) + (size_t)j0 * 8192;
    #pragma unroll
    for (int it = 0; it < 8; ++it) {
        const int chunk = it * 512 + tid;
        __builtin_amdgcn_global_load_lds(
            (const __attribute__((address_space(1))) void*)(bsrc + chunk * 16),
            (__attribute__((address_space(3))) void*)(Bs + chunk * 16), 16, 0, 0);
    }
    __syncthreads();

    const int ksw = (l16 & 7) << 4;   // == (h&7)<<4 for h = eh*16+l16
    #pragma unroll 2
    for (int jj = 0; jj < 8; ++jj) {
        bf16x8 bfr[2][4];
        #pragma unroll
        for (int eh = 0; eh < 2; ++eh)
            #pragma unroll
            for (int kk = 0; kk < 4; ++kk)
                bfr[eh][kk] = *reinterpret_cast<const bf16x8*>(
                    Bs + jj * 8192 + (eh * 16 + l16) * 256 + ((kk * 64 + l4 * 16) ^ ksw));

        const f32x4 zero = {0.f, 0.f, 0.f, 0.f};
        f32x4 acc[2][2];
        acc[0][0] = zero; acc[0][1] = zero; acc[1][0] = zero; acc[1][1] = zero;
        #pragma unroll
        for (int kk = 0; kk < 4; ++kk) {
            acc[0][0] = __builtin_amdgcn_mfma_f32_16x16x32_bf16(afr[0][kk], bfr[0][kk], acc[0][0], 0, 0, 0);
            acc[0][1] = __builtin_amdgcn_mfma_f32_16x16x32_bf16(afr[0][kk], bfr[1][kk], acc[0][1], 0, 0, 0);
            acc[1][0] = __builtin_amdgcn_mfma_f32_16x16x32_bf16(afr[1][kk], bfr[0][kk], acc[1][0], 0, 0, 0);
            acc[1][1] = __builtin_amdgcn_mfma_f32_16x16x32_bf16(afr[1][kk], bfr[1][kk], acc[1][1], 0, 0, 0);
        }
        char* pb = reinterpret_cast<char*>(OU) + (size_t)(i * R_DIM + j0 + jj) * 2048;
        #pragma unroll
        for (int ch = 0; ch < 2; ++ch)
            #pragma unroll
            for (int eh = 0; eh < 2; ++eh) {
                const int e  = eh * 16 + l16;          // D col = e
                const int c0 = ch * 16 + l4 * 4;       // D rows = 4 consecutive c
                ushort4 o;
                o.x = f2bf(acc[ch][eh][0]);
                o.y = f2bf(acc[ch][eh][1]);
                o.z = f2bf(acc[ch][eh][2]);
                o.w = f2bf(acc[ch][eh][3]);
                *reinterpret_cast<ushort4*>(pb + e * 64 + c0 * 2) = o;
            }
    }
}

// ---------------------------------------------------------------------------
// Kernel 2b (split path): GEMM  out[p][z] = OU[p][:] . wTp[z][:] + b_out, *rcp
// M=65536, K=1024, N=128. BM=128, BK=64, 512 thr (4Mx2N waves), dbuf
// global_load_lds staging with pre-swizzled sources; 512 wgs (all resident).
// ---------------------------------------------------------------------------
__device__ __forceinline__ void stage_tiles(const char* OUb, const char* Wb,
                                            char* As, char* Ws, int tid, int ks)
{
    #pragma unroll
    for (int it = 0; it < 2; ++it) {
        const int idx = it * 512 + tid;                 // 0..1023
        const int row = idx >> 3, kb = idx & 7;
        const int kByte = ks * 128 + ((kb * 16) ^ ((row & 7) << 4));
        __builtin_amdgcn_global_load_lds(
            (const __attribute__((address_space(1))) void*)(OUb + (size_t)row * 2048 + kByte),
            (__attribute__((address_space(3))) void*)(As + idx * 16), 16, 0, 0);
        __builtin_amdgcn_global_load_lds(
            (const __attribute__((address_space(1))) void*)(Wb + (size_t)row * 2048 + kByte),
            (__attribute__((address_space(3))) void*)(Ws + idx * 16), 16, 0, 0);
    }
}

__global__ __launch_bounds__(512)
void gemm_kernel(const __hip_bfloat16* __restrict__ OU,
                 const __hip_bfloat16* __restrict__ wTp,
                 const float* __restrict__ b_out,
                 const float* __restrict__ rcp,
                 float* __restrict__ out)
{
    __shared__ char As[2][16384];
    __shared__ char Ws[2][16384];
    const int tid  = threadIdx.x;
    const int wave = tid >> 6, lane = tid & 63;
    const int l16 = lane & 15, l4 = lane >> 4;
    const int wm = wave >> 1, wn = wave & 1;       // 4 M x 2 N
    const int p0 = blockIdx.x * 128;

    const char* OUb = reinterpret_cast<const char*>(OU) + (size_t)p0 * 2048;
    const char* Wb  = reinterpret_cast<const char*>(wTp);

    const f32x4 zero = {0.f, 0.f, 0.f, 0.f};
    f32x4 acc[2][4];
    #pragma unroll
    for (int mt = 0; mt < 2; ++mt)
        #pragma unroll
        for (int nt = 0; nt < 4; ++nt) acc[mt][nt] = zero;

    stage_tiles(OUb, Wb, As[0], Ws[0], tid, 0);
    __syncthreads();

    for (int ks = 0; ks < 16; ++ks) {
        const int cur = ks & 1;
        if (ks < 15) stage_tiles(OUb, Wb, As[cur ^ 1], Ws[cur ^ 1], tid, ks + 1);
        #pragma unroll
        for (int kk = 0; kk < 2; ++kk) {
            bf16x8 af[2], bf[4];
            #pragma unroll
            for (int mt = 0; mt < 2; ++mt) {
                const int row = wm * 32 + mt * 16 + l16;
                af[mt] = *reinterpret_cast<const bf16x8*>(
                    As[cur] + row * 128 + ((kk * 64 + l4 * 16) ^ ((row & 7) << 4)));
            }
            #pragma unroll
            for (int nt = 0; nt < 4; ++nt) {
                const int zr = wn * 64 + nt * 16 + l16;
                bf[nt] = *reinterpret_cast<const bf16x8*>(
                    Ws[cur] + zr * 128 + ((kk * 64 + l4 * 16) ^ ((zr & 7) << 4)));
            }
            #pragma unroll
            for (int mt = 0; mt < 2; ++mt)
                #pragma unroll
                for (int nt = 0; nt < 4; ++nt)
                    acc[mt][nt] = __builtin_amdgcn_mfma_f32_16x16x32_bf16(af[mt], bf[nt], acc[mt][nt], 0, 0, 0);
        }
        __syncthreads();
    }

    // epilogue: +bias, *rcp, nontemporal store
    float rc[2][4];
    #pragma unroll
    for (int mt = 0; mt < 2; ++mt)
        #pragma unroll
        for (int t = 0; t < 4; ++t)
            rc[mt][t] = rcp[p0 + wm * 32 + mt * 16 + l4 * 4 + t];
    #pragma unroll
    for (int nt = 0; nt < 4; ++nt) {
        const int z = wn * 64 + nt * 16 + l16;
        const float bo = b_out[z];
        #pragma unroll
        for (int mt = 0; mt < 2; ++mt)
            #pragma unroll
            for (int t = 0; t < 4; ++t) {
                const int p = p0 + wm * 32 + mt * 16 + l4 * 4 + t;
                __builtin_nontemporal_store((acc[mt][nt][t] + bo) * rc[mt][t],
                                            &out[(size_t)p * CZ + z]);
            }
    }
}

// ---------------------------------------------------------------------------
// Fallback (small ws): v5 fused kernel (reads b_t UNSWIZZLED)
// ---------------------------------------------------------------------------
__global__ __launch_bounds__(512)
void fused_kernel(const __hip_bfloat16* __restrict__ a_t,
                  const __hip_bfloat16* __restrict__ b_t,
                  const __hip_bfloat16* __restrict__ wT,
                  const float* __restrict__ b_out,
                  const float* __restrict__ recip,
                  float* __restrict__ out)
{
    __shared__ __hip_bfloat16 outer_lds[32 * 1024];   // 64 KB
    const int tid  = threadIdx.x;
    const int wave = tid >> 6, lane = tid & 63;
    const int l16 = lane & 15, l4 = lane >> 4;
    const int i0 = blockIdx.y * 8, j0 = blockIdx.x * 4;
    char* ldsb = reinterpret_cast<char*>(outer_lds);

    {
        const int i = i0 + wave;
        const __hip_bfloat16* abase = a_t + (size_t)i * (CH * S_DIM) + l16 * S_DIM + l4 * 8;
        bf16x8 afr[2][4];
        #pragma unroll
        for (int ch = 0; ch < 2; ++ch)
            #pragma unroll
            for (int kk = 0; kk < 4; ++kk)
                afr[ch][kk] = *reinterpret_cast<const bf16x8*>(abase + ch * 16 * S_DIM + kk * 32);

        #pragma unroll
        for (int j = 0; j < 4; ++j) {
            const __hip_bfloat16* bb = b_t + (size_t)(j0 + j) * (CH * S_DIM) + l16 * S_DIM + l4 * 8;
            bf16x8 bfr[2][4];
            #pragma unroll
            for (int eh = 0; eh < 2; ++eh)
                #pragma unroll
                for (int kk = 0; kk < 4; ++kk)
                    bfr[eh][kk] = *reinterpret_cast<const bf16x8*>(bb + eh * 16 * S_DIM + kk * 32);
            const f32x4 zero = {0.f, 0.f, 0.f, 0.f};
            f32x4 acc[2][2];
            acc[0][0] = zero; acc[0][1] = zero; acc[1][0] = zero; acc[1][1] = zero;
            #pragma unroll
            for (int kk = 0; kk < 4; ++kk) {
                acc[0][0] = __builtin_amdgcn_mfma_f32_16x16x32_bf16(afr[0][kk], bfr[0][kk], acc[0][0], 0, 0, 0);
                acc[0][1] = __builtin_amdgcn_mfma_f32_16x16x32_bf16(afr[0][kk], bfr[1][kk], acc[0][1], 0, 0, 0);
                acc[1][0] = __builtin_amdgcn_mfma_f32_16x16x32_bf16(afr[1][kk], bfr[0][kk], acc[1][0], 0, 0, 0);
                acc[1][1] = __builtin_amdgcn_mfma_f32_16x16x32_bf16(afr[1][kk], bfr[1][kk], acc[1][1], 0, 0, 0);
            }
            const int pair = wave * 4 + j;
            char* rowb = ldsb + pair * 2048;
            const int psw = (pair & 7) << 4;
            #pragma unroll
            for (int ch = 0; ch < 2; ++ch)
                #pragma unroll
                for (int eh = 0; eh < 2; ++eh) {
                    const int e  = eh * 16 + l16;
                    const int c0 = ch * 16 + l4 * 4;
                    const int byte = (e * 64 + c0 * 2) ^ ((e & 3) << 4) ^ psw;
                    ushort4 o;
                    o.x = f2bf(acc[ch][eh][0]);
                    o.y = f2bf(acc[ch][eh][1]);
                    o.z = f2bf(acc[ch][eh][2]);
                    o.w = f2bf(acc[ch][eh][3]);
                    *reinterpret_cast<ushort4*>(rowb + byte) = o;
                }
        }
    }
    __syncthreads();

    {
        const __hip_bfloat16* wbase = wT + (size_t)(wave * 16 + l16) * 1024 + l4 * 8;
        const f32x4 zero = {0.f, 0.f, 0.f, 0.f};
        f32x4 pacc[2];
        pacc[0] = zero; pacc[1] = zero;
        #pragma unroll 4
        for (int kb = 0; kb < 32; ++kb) {
            const bf16x8 bfc = *reinterpret_cast<const bf16x8*>(wbase + kb * 32);
            #pragma unroll
            for (int mt = 0; mt < 2; ++mt) {
                const int pr = mt * 16 + l16;
                const bf16x8 af = *reinterpret_cast<const bf16x8*>(
                    ldsb + pr * 2048 +
                    ((kb * 64 + l4 * 16) ^ ((kb & 3) << 4) ^ ((pr & 7) << 4)));
                pacc[mt] = __builtin_amdgcn_mfma_f32_16x16x32_bf16(af, bfc, pacc[mt], 0, 0, 0);
            }
        }
        const int z = wave * 16 + l16;
        const float bo = b_out[z];
        #pragma unroll
        for (int mt = 0; mt < 2; ++mt)
            #pragma unroll
            for (int t = 0; t < 4; ++t) {
                const int pl = mt * 16 + l4 * 4 + t;
                const int oi = i0 + (pl >> 2), oj = j0 + (pl & 3);
                out[((size_t)oi * R_DIM + oj) * CZ + z] =
                    (pacc[mt][t] + bo) * recip[oi * R_DIM + oj];
            }
    }
}

// ---------------------------------------------------------------------------
extern "C" void kernel_launch(void* const* d_in, const int* in_sizes, int n_in,
                              void* d_out, int out_size, void* d_ws, size_t ws_size,
                              hipStream_t stream)
{
    const float* m     = (const float*)d_in[0];
    const float* mask  = (const float*)d_in[1];
    const float* ln_s  = (const float*)d_in[2];
    const float* ln_b  = (const float*)d_in[3];
    const float* w1    = (const float*)d_in[4];
    const float* b1    = (const float*)d_in[5];
    const float* w2    = (const float*)d_in[6];
    const float* b2    = (const float*)d_in[7];
    const float* w_out = (const float*)d_in[8];
    const float* b_out = (const float*)d_in[9];
    float* out = (float*)d_out;

    char* ws = (char*)d_ws;
    __hip_bfloat16* a_t   = (__hip_bfloat16*)(ws);                                     // 2 MB
    __hip_bfloat16* b_t   = (__hip_bfloat16*)(ws + (size_t)(2u << 20));                // 2 MB
    __hip_bfloat16* wTp   = (__hip_bfloat16*)(ws + (size_t)(4u << 20));                // 256 KB
    float*          rcp   = (float*)(ws + (size_t)(4u << 20) + (size_t)(256u << 10));  // 256 KB
    __hip_bfloat16* w12T  = (__hip_bfloat16*)(ws + (size_t)(4u << 20) + (size_t)(512u << 10)); // 32 KB
    float*          maskT = (float*)(ws + (size_t)(4u << 20) + (size_t)(544u << 10));  // 128 KB
    __hip_bfloat16* OU    = (__hip_bfloat16*)(ws + (size_t)(5u << 20));                // 128 MB

    const size_t need = (size_t)(5u << 20) + (size_t)65536 * 1024 * 2;
    const int use_split = (ws_size >= need) ? 1 : 0;

    prep1_kernel<<<704, 256, 0, stream>>>(w1, w2, w_out, mask, w12T, wTp, maskT);
    prep2_kernel<<<R_DIM, R_DIM, 0, stream>>>(maskT, rcp);
    ln_proj_kernel<<<1024, 256, 0, stream>>>(m, mask, ln_s, ln_b, w12T, b1, b2,
                                             a_t, b_t, use_split);
    if (use_split) {
        outer_kernel<<<dim3(32, 32), 512, 0, stream>>>(a_t, b_t, OU);
        gemm_kernel<<<512, 512, 0, stream>>>(OU, wTp, b_out, rcp, out);
    } else {
        fused_kernel<<<dim3(64, 32), 512, 0, stream>>>(a_t, b_t, wTp, b_out, rcp, out);
    }
}